// Round 12
// baseline (199.635 us; speedup 1.0000x reference)
//
#include <hip/hip_runtime.h>

typedef __attribute__((ext_vector_type(8))) short short8;
typedef __attribute__((ext_vector_type(4))) float f32x4;

#define B_ 2
#define S_ 512
#define D_ 768
#define NH 12
#define HD 64

__device__ inline short f2bf(float f) {
    union { float f; unsigned u; } v; v.f = f;
    unsigned r = v.u + 0x7fffu + ((v.u >> 16) & 1u);
    return (short)(r >> 16);
}

__device__ __forceinline__ float bf2f(short s) {
    union { unsigned u; float f; } v;
    v.u = ((unsigned)(unsigned short)s) << 16;
    return v.f;
}

__device__ __forceinline__ f32x4 ntload4(const float* p) {
    return __builtin_nontemporal_load((const f32x4*)p);
}

// ---------------------------------------------------------------------------
// Kernel 1: QKV projection, bf16 MFMA, fp32 accumulate.
// q -> qbf (bf16, scaled 1/8) (b,n,s,h); k -> kbf (bf16) (b,n,s,h);
// v -> vbf (bf16, TRANSPOSED) (b,n,h,s) via LDS transpose.
// ---------------------------------------------------------------------------
__global__ __launch_bounds__(256) void qkv_gemm(
    const float* __restrict__ hidden,
    const float* __restrict__ Wq, const float* __restrict__ Wk, const float* __restrict__ Wv,
    const float* __restrict__ bq, const float* __restrict__ bk, const float* __restrict__ bv,
    short* __restrict__ qbf, short* __restrict__ kbf, short* __restrict__ vbf)
{
    __shared__ short hs[64 * 72];
    __shared__ short wt[64 * 72];

    const int mt = blockIdx.x, nt = blockIdx.y, mat = blockIdx.z;
    const int m0 = mt * 64, n0 = nt * 64;
    const float* W    = (mat == 0) ? Wq : ((mat == 1) ? Wk : Wv);
    const float* bias = (mat == 0) ? bq : ((mat == 1) ? bk : bv);

    const int tid = threadIdx.x;
    const int w = tid >> 6, l = tid & 63;
    const int sr = tid >> 2, sc = (tid & 3) * 16;

    f32x4 acc[4];
    #pragma unroll
    for (int i = 0; i < 4; ++i) acc[i] = (f32x4){0.f, 0.f, 0.f, 0.f};

    const int arow = (w * 16 + (l & 15)) * 72 + (l >> 4) * 8;

    for (int kt = 0; kt < 12; ++kt) {
        const int d0 = kt * 64;
        if (kt) __syncthreads();
        {
            const float4* sa = (const float4*)(hidden + (size_t)(m0 + sr) * D_ + d0 + sc);
            float4 x0 = sa[0], x1 = sa[1], x2 = sa[2], x3 = sa[3];
            short8 p0 = {f2bf(x0.x), f2bf(x0.y), f2bf(x0.z), f2bf(x0.w),
                         f2bf(x1.x), f2bf(x1.y), f2bf(x1.z), f2bf(x1.w)};
            short8 p1 = {f2bf(x2.x), f2bf(x2.y), f2bf(x2.z), f2bf(x2.w),
                         f2bf(x3.x), f2bf(x3.y), f2bf(x3.z), f2bf(x3.w)};
            *(short8*)&hs[sr * 72 + sc]     = p0;
            *(short8*)&hs[sr * 72 + sc + 8] = p1;
            const float4* sb = (const float4*)(W + (size_t)(n0 + sr) * D_ + d0 + sc);
            float4 y0 = sb[0], y1 = sb[1], y2 = sb[2], y3 = sb[3];
            short8 q0 = {f2bf(y0.x), f2bf(y0.y), f2bf(y0.z), f2bf(y0.w),
                         f2bf(y1.x), f2bf(y1.y), f2bf(y1.z), f2bf(y1.w)};
            short8 q1 = {f2bf(y2.x), f2bf(y2.y), f2bf(y2.z), f2bf(y2.w),
                         f2bf(y3.x), f2bf(y3.y), f2bf(y3.z), f2bf(y3.w)};
            *(short8*)&wt[sr * 72 + sc]     = q0;
            *(short8*)&wt[sr * 72 + sc + 8] = q1;
        }
        __syncthreads();
        short8 a0 = *(const short8*)&hs[arow];
        short8 a1 = *(const short8*)&hs[arow + 32];
        #pragma unroll
        for (int ct = 0; ct < 4; ++ct) {
            const int brow = (ct * 16 + (l & 15)) * 72 + (l >> 4) * 8;
            short8 b0 = *(const short8*)&wt[brow];
            short8 b1 = *(const short8*)&wt[brow + 32];
            acc[ct] = __builtin_amdgcn_mfma_f32_16x16x32_bf16(a0, b0, acc[ct], 0, 0, 0);
            acc[ct] = __builtin_amdgcn_mfma_f32_16x16x32_bf16(a1, b1, acc[ct], 0, 0, 0);
        }
    }

    if (mat == 2) {
        __syncthreads();
        #pragma unroll
        for (int ct = 0; ct < 4; ++ct) {
            #pragma unroll
            for (int rr = 0; rr < 4; ++rr) {
                const int m_l = w * 16 + (l >> 4) * 4 + rr;
                const int n_l = ct * 16 + (l & 15);
                hs[n_l * 68 + m_l] = f2bf(acc[ct][rr] + bias[n0 + n_l]);
            }
        }
        __syncthreads();
        const int b   = m0 >> 9;
        const int s0b = m0 & 511;
        #pragma unroll
        for (int j = 0; j < 2; ++j) {
            const int idx  = j * 256 + tid;
            const int h    = idx >> 3;
            const int sseg = (idx & 7) * 8;
            short8 vv = *(const short8*)&hs[h * 68 + sseg];
            *(short8*)(vbf + ((size_t)(b * NH + nt) * HD + h) * S_ + s0b + sseg) = vv;
        }
    } else {
        #pragma unroll
        for (int ct = 0; ct < 4; ++ct) {
            #pragma unroll
            for (int rr = 0; rr < 4; ++rr) {
                const int m_l = w * 16 + (l >> 4) * 4 + rr;
                const int n_l = ct * 16 + (l & 15);
                const int m = m0 + m_l;
                const int b = m >> 9, s = m & 511;
                float v = acc[ct][rr] + bias[n0 + n_l];
                const size_t dst = (((size_t)(b * NH + nt) * S_) + s) * HD + n_l;
                if (mat == 0) qbf[dst] = f2bf(v * 0.125f);
                else          kbf[dst] = f2bf(v);
            }
        }
    }
}

// ---------------------------------------------------------------------------
// Kernel 2: qks = qs . K^T + mask, batched over (b,n). 64x64 tile.
// Output layout (b, n, s, k). ~5 µs, all inputs L2-resident.
// ---------------------------------------------------------------------------
__global__ __launch_bounds__(256) void score_qk(
    const short* __restrict__ qbf, const short* __restrict__ kbf,
    const float* __restrict__ mask, float* __restrict__ qks)
{
    __shared__ short qa[64 * 72];
    __shared__ short kb[64 * 72];

    const int st = blockIdx.x, ktile = blockIdx.y, z = blockIdx.z;
    const int b = z / NH, n = z % NH;
    const int s0 = st * 64, k0 = ktile * 64;
    const int tid = threadIdx.x;
    const int w = tid >> 6, l = tid & 63;
    const int sr = tid >> 2, sc = (tid & 3) * 16;

    {
        const short8* sa = (const short8*)(qbf + (((size_t)(b * NH + n) * S_) + s0 + sr) * HD + sc);
        *(short8*)&qa[sr * 72 + sc]     = sa[0];
        *(short8*)&qa[sr * 72 + sc + 8] = sa[1];
        const short8* sb = (const short8*)(kbf + (((size_t)(b * NH + n) * S_) + k0 + sr) * HD + sc);
        *(short8*)&kb[sr * 72 + sc]     = sb[0];
        *(short8*)&kb[sr * 72 + sc + 8] = sb[1];
    }
    __syncthreads();

    f32x4 acc[4];
    #pragma unroll
    for (int i = 0; i < 4; ++i) acc[i] = (f32x4){0.f, 0.f, 0.f, 0.f};

    const int arow = (w * 16 + (l & 15)) * 72 + (l >> 4) * 8;
    short8 a0 = *(const short8*)&qa[arow];
    short8 a1 = *(const short8*)&qa[arow + 32];
    #pragma unroll
    for (int ct = 0; ct < 4; ++ct) {
        const int brow = (ct * 16 + (l & 15)) * 72 + (l >> 4) * 8;
        short8 b0 = *(const short8*)&kb[brow];
        short8 b1 = *(const short8*)&kb[brow + 32];
        acc[ct] = __builtin_amdgcn_mfma_f32_16x16x32_bf16(a0, b0, acc[ct], 0, 0, 0);
        acc[ct] = __builtin_amdgcn_mfma_f32_16x16x32_bf16(a1, b1, acc[ct], 0, 0, 0);
    }

    #pragma unroll
    for (int ct = 0; ct < 4; ++ct) {
        const float mv = mask[b * S_ + k0 + ct * 16 + (l & 15)];
        #pragma unroll
        for (int rr = 0; rr < 4; ++rr) {
            const int s_l = w * 16 + (l >> 4) * 4 + rr;
            qks[(((size_t)(b * NH + n) * S_) + s0 + s_l) * S_ + k0 + ct * 16 + (l & 15)]
                = acc[ct][rr] + mv;
        }
    }
}

// ---------------------------------------------------------------------------
// Kernel 3: FUSED rel-stream + score-add + softmax + PV. One block per (b,s).
// Grid (s=512, b=2) = 1024 blocks = 4 blocks/CU (all co-resident), 256 thr.
// Phase A: wave w streams 8 k-subtiles (NT 12x dwordx4 -> rsum -> bf16 ->
//          MFMA vs q A-frag) writing rel scores into LDS sc[12][520].
// Phase B: sc += qks (QK+mask, precomputed).
// Phase C: softmax rows in fp32 (3 rows/wave).
// Phase D: PV: thread owns 3 (n,h); P row LDS-broadcast, V^T bf16 contiguous.
// The B/C/D work of earlier blocks hides under later blocks' A-streams.
// ---------------------------------------------------------------------------
__global__ __launch_bounds__(256) void fused_rel(
    const short* __restrict__ qbf,
    const float* __restrict__ rel1, const float* __restrict__ rel2, const float* __restrict__ rel3,
    const float* __restrict__ qks, const short* __restrict__ vbf,
    float* __restrict__ out)
{
    __shared__ float sc[NH][520];    // 24.96 KB

    const int s = blockIdx.x;
    const int b = blockIdx.y;
    const int tid = threadIdx.x;
    const int w = tid >> 6, l = tid & 63;

    const int rowsel = l & 15;       // A: n-row / B: k-row / D: k-col
    const int hc     = (l >> 4) * 8; // h-chunk base

    // q A-fragment (heads 12..15 zero), loaded once, reused 8x.
    short8 a0 = {0, 0, 0, 0, 0, 0, 0, 0};
    short8 a1 = {0, 0, 0, 0, 0, 0, 0, 0};
    if (rowsel < NH) {
        const short* qp = qbf + (((size_t)(b * NH + rowsel) * S_) + s) * HD;
        a0 = *(const short8*)(qp + hc);
        a1 = *(const short8*)(qp + hc + 32);
    }

    const size_t rbase = ((size_t)(b * S_ + s)) * S_ * HD;

    // --- Phase A: rel stream + MFMA into LDS ---
    for (int t = 0; t < 8; ++t) {
        const int kc = t * 4 + w;    // k-subtile 0..31
        const size_t ro = rbase + (size_t)(kc * 16 + rowsel) * HD + hc;

        f32x4 p0a = ntload4(rel1 + ro);
        f32x4 p0b = ntload4(rel1 + ro + 4);
        f32x4 q0a = ntload4(rel1 + ro + 32);
        f32x4 q0b = ntload4(rel1 + ro + 36);
        f32x4 p1a = ntload4(rel2 + ro);
        f32x4 p1b = ntload4(rel2 + ro + 4);
        f32x4 q1a = ntload4(rel2 + ro + 32);
        f32x4 q1b = ntload4(rel2 + ro + 36);
        f32x4 p2a = ntload4(rel3 + ro);
        f32x4 p2b = ntload4(rel3 + ro + 4);
        f32x4 q2a = ntload4(rel3 + ro + 32);
        f32x4 q2b = ntload4(rel3 + ro + 36);

        short8 b0 = {
            f2bf(p0a.x + p1a.x + p2a.x), f2bf(p0a.y + p1a.y + p2a.y),
            f2bf(p0a.z + p1a.z + p2a.z), f2bf(p0a.w + p1a.w + p2a.w),
            f2bf(p0b.x + p1b.x + p2b.x), f2bf(p0b.y + p1b.y + p2b.y),
            f2bf(p0b.z + p1b.z + p2b.z), f2bf(p0b.w + p1b.w + p2b.w)};
        short8 b1 = {
            f2bf(q0a.x + q1a.x + q2a.x), f2bf(q0a.y + q1a.y + q2a.y),
            f2bf(q0a.z + q1a.z + q2a.z), f2bf(q0a.w + q1a.w + q2a.w),
            f2bf(q0b.x + q1b.x + q2b.x), f2bf(q0b.y + q1b.y + q2b.y),
            f2bf(q0b.z + q1b.z + q2b.z), f2bf(q0b.w + q1b.w + q2b.w)};

        f32x4 acc = (f32x4){0.f, 0.f, 0.f, 0.f};
        acc = __builtin_amdgcn_mfma_f32_16x16x32_bf16(a0, b0, acc, 0, 0, 0);
        acc = __builtin_amdgcn_mfma_f32_16x16x32_bf16(a1, b1, acc, 0, 0, 0);

        const int kg = kc * 16 + rowsel;
        #pragma unroll
        for (int rr = 0; rr < 4; ++rr) {
            const int n = (l >> 4) * 4 + rr;
            if (n < NH) sc[n][kg] = acc[rr];
        }
    }
    __syncthreads();

    // --- Phase B: += QK + mask scores ---
    #pragma unroll
    for (int j = 0; j < 6; ++j) {
        const int fidx = j * 256 + tid;      // 0..1535 = 12 rows x 128 f4
        const int row  = fidx >> 7;
        const int c4   = (fidx & 127) * 4;
        float4 qv = *(const float4*)(qks + (((size_t)(b * NH + row) * S_) + s) * S_ + c4);
        float4 cur = *(const float4*)&sc[row][c4];
        cur.x += qv.x; cur.y += qv.y; cur.z += qv.z; cur.w += qv.w;
        *(float4*)&sc[row][c4] = cur;
    }
    __syncthreads();

    // --- Phase C: softmax (PB-Relax == plain softmax). Wave w: rows w,w+4,w+8.
    for (int r = 0; r < 3; ++r) {
        const int row = r * 4 + w;
        float vals[8];
        float m = -1e30f;
        #pragma unroll
        for (int i = 0; i < 8; ++i) { vals[i] = sc[row][l + 64 * i]; m = fmaxf(m, vals[i]); }
        #pragma unroll
        for (int off = 32; off >= 1; off >>= 1) m = fmaxf(m, __shfl_xor(m, off));
        float sum = 0.f;
        #pragma unroll
        for (int i = 0; i < 8; ++i) { vals[i] = __expf(vals[i] - m); sum += vals[i]; }
        #pragma unroll
        for (int off = 32; off >= 1; off >>= 1) sum += __shfl_xor(sum, off);
        const float inv = 1.0f / sum;
        #pragma unroll
        for (int i = 0; i < 8; ++i) sc[row][l + 64 * i] = vals[i] * inv;
    }
    __syncthreads();

    // --- Phase D: PV. Thread owns (n,h) = tid, tid+256, tid+512.
    // P row is wave-uniform (LDS broadcast); V^T row contiguous bf16.
    float res[3];
    #pragma unroll
    for (int pi = 0; pi < 3; ++pi) {
        const int p = pi * 256 + tid;
        const int n = p >> 6, h = p & 63;
        const short* vp = vbf + ((size_t)(b * NH + n) * HD + h) * S_;
        float ax = 0.f, ay = 0.f, az = 0.f, aw = 0.f;
        #pragma unroll 4
        for (int k = 0; k < S_; k += 8) {
            short8 vv = *(const short8*)(vp + k);
            float4 pa = *(const float4*)&sc[n][k];
            float4 pb = *(const float4*)&sc[n][k + 4];
            ax += pa.x * bf2f(vv[0]);
            ay += pa.y * bf2f(vv[1]);
            az += pa.z * bf2f(vv[2]);
            aw += pa.w * bf2f(vv[3]);
            ax += pb.x * bf2f(vv[4]);
            ay += pb.y * bf2f(vv[5]);
            az += pb.z * bf2f(vv[6]);
            aw += pb.w * bf2f(vv[7]);
        }
        res[pi] = (ax + ay) + (az + aw);
    }
    float* orow = out + ((size_t)(b * S_ + s)) * D_;
    #pragma unroll
    for (int pi = 0; pi < 3; ++pi)
        orow[pi * 256 + tid] = res[pi];
}

extern "C" void kernel_launch(void* const* d_in, const int* in_sizes, int n_in,
                              void* d_out, int out_size, void* d_ws, size_t ws_size,
                              hipStream_t stream) {
    const float* hidden = (const float*)d_in[0];
    const float* mask   = (const float*)d_in[1];
    const float* rel1   = (const float*)d_in[2];
    const float* rel2   = (const float*)d_in[3];
    const float* rel3   = (const float*)d_in[4];
    const float* Wq     = (const float*)d_in[5];
    const float* bq     = (const float*)d_in[6];
    const float* Wk     = (const float*)d_in[7];
    const float* bk     = (const float*)d_in[8];
    const float* Wv     = (const float*)d_in[9];
    const float* bv     = (const float*)d_in[10];
    float* out = (float*)d_out;

    const size_t per = (size_t)B_ * NH * S_ * HD;   // 786432
    short* qbf = (short*)d_ws;                       // 1.5 MB
    short* kbf = qbf + per;                          // 1.5 MB
    short* vbf = kbf + per;                          // 1.5 MB (b,n,h,s)
    float* qks = (float*)(vbf + per);                // 25 MB (b,n,s,k)

    qkv_gemm<<<dim3(16, 12, 3), 256, 0, stream>>>(hidden, Wq, Wk, Wv, bq, bk, bv, qbf, kbf, vbf);
    score_qk<<<dim3(8, 8, 24), 256, 0, stream>>>(qbf, kbf, mask, qks);
    fused_rel<<<dim3(S_, B_), 256, 0, stream>>>(qbf, rel1, rel2, rel3, qks, vbf, out);
}

// Round 13
// 134.060 us; speedup vs baseline: 1.4891x; 1.4891x over previous
//
#include <hip/hip_runtime.h>

typedef __attribute__((ext_vector_type(8))) short short8;
typedef __attribute__((ext_vector_type(4))) float f32x4;

#define B_ 2
#define S_ 512
#define D_ 768
#define NH 12
#define HD 64

__device__ inline short f2bf(float f) {
    union { float f; unsigned u; } v; v.f = f;
    unsigned r = v.u + 0x7fffu + ((v.u >> 16) & 1u);
    return (short)(r >> 16);
}

__device__ __forceinline__ f32x4 ntload4(const float* p) {
    return __builtin_nontemporal_load((const f32x4*)p);
}

// ---------------------------------------------------------------------------
// Kernel 1: QKV projection, bf16 MFMA, fp32 accumulate.
// q -> qbf (bf16, scaled 1/8) (b,n,s,h); k -> kbf (bf16) (b,n,s,h);
// v -> vbf (bf16, TRANSPOSED) (b,n,h,s) via LDS transpose.
// ---------------------------------------------------------------------------
__global__ __launch_bounds__(256) void qkv_gemm(
    const float* __restrict__ hidden,
    const float* __restrict__ Wq, const float* __restrict__ Wk, const float* __restrict__ Wv,
    const float* __restrict__ bq, const float* __restrict__ bk, const float* __restrict__ bv,
    short* __restrict__ qbf, short* __restrict__ kbf, short* __restrict__ vbf)
{
    __shared__ short hs[64 * 72];
    __shared__ short wt[64 * 72];

    const int mt = blockIdx.x, nt = blockIdx.y, mat = blockIdx.z;
    const int m0 = mt * 64, n0 = nt * 64;
    const float* W    = (mat == 0) ? Wq : ((mat == 1) ? Wk : Wv);
    const float* bias = (mat == 0) ? bq : ((mat == 1) ? bk : bv);

    const int tid = threadIdx.x;
    const int w = tid >> 6, l = tid & 63;
    const int sr = tid >> 2, sc = (tid & 3) * 16;

    f32x4 acc[4];
    #pragma unroll
    for (int i = 0; i < 4; ++i) acc[i] = (f32x4){0.f, 0.f, 0.f, 0.f};

    const int arow = (w * 16 + (l & 15)) * 72 + (l >> 4) * 8;

    for (int kt = 0; kt < 12; ++kt) {
        const int d0 = kt * 64;
        if (kt) __syncthreads();
        {
            const float4* sa = (const float4*)(hidden + (size_t)(m0 + sr) * D_ + d0 + sc);
            float4 x0 = sa[0], x1 = sa[1], x2 = sa[2], x3 = sa[3];
            short8 p0 = {f2bf(x0.x), f2bf(x0.y), f2bf(x0.z), f2bf(x0.w),
                         f2bf(x1.x), f2bf(x1.y), f2bf(x1.z), f2bf(x1.w)};
            short8 p1 = {f2bf(x2.x), f2bf(x2.y), f2bf(x2.z), f2bf(x2.w),
                         f2bf(x3.x), f2bf(x3.y), f2bf(x3.z), f2bf(x3.w)};
            *(short8*)&hs[sr * 72 + sc]     = p0;
            *(short8*)&hs[sr * 72 + sc + 8] = p1;
            const float4* sb = (const float4*)(W + (size_t)(n0 + sr) * D_ + d0 + sc);
            float4 y0 = sb[0], y1 = sb[1], y2 = sb[2], y3 = sb[3];
            short8 q0 = {f2bf(y0.x), f2bf(y0.y), f2bf(y0.z), f2bf(y0.w),
                         f2bf(y1.x), f2bf(y1.y), f2bf(y1.z), f2bf(y1.w)};
            short8 q1 = {f2bf(y2.x), f2bf(y2.y), f2bf(y2.z), f2bf(y2.w),
                         f2bf(y3.x), f2bf(y3.y), f2bf(y3.z), f2bf(y3.w)};
            *(short8*)&wt[sr * 72 + sc]     = q0;
            *(short8*)&wt[sr * 72 + sc + 8] = q1;
        }
        __syncthreads();
        short8 a0 = *(const short8*)&hs[arow];
        short8 a1 = *(const short8*)&hs[arow + 32];
        #pragma unroll
        for (int ct = 0; ct < 4; ++ct) {
            const int brow = (ct * 16 + (l & 15)) * 72 + (l >> 4) * 8;
            short8 b0 = *(const short8*)&wt[brow];
            short8 b1 = *(const short8*)&wt[brow + 32];
            acc[ct] = __builtin_amdgcn_mfma_f32_16x16x32_bf16(a0, b0, acc[ct], 0, 0, 0);
            acc[ct] = __builtin_amdgcn_mfma_f32_16x16x32_bf16(a1, b1, acc[ct], 0, 0, 0);
        }
    }

    if (mat == 2) {
        __syncthreads();
        #pragma unroll
        for (int ct = 0; ct < 4; ++ct) {
            #pragma unroll
            for (int rr = 0; rr < 4; ++rr) {
                const int m_l = w * 16 + (l >> 4) * 4 + rr;
                const int n_l = ct * 16 + (l & 15);
                hs[n_l * 68 + m_l] = f2bf(acc[ct][rr] + bias[n0 + n_l]);
            }
        }
        __syncthreads();
        const int b   = m0 >> 9;
        const int s0b = m0 & 511;
        #pragma unroll
        for (int j = 0; j < 2; ++j) {
            const int idx  = j * 256 + tid;
            const int h    = idx >> 3;
            const int sseg = (idx & 7) * 8;
            short8 vv = *(const short8*)&hs[h * 68 + sseg];
            *(short8*)(vbf + ((size_t)(b * NH + nt) * HD + h) * S_ + s0b + sseg) = vv;
        }
    } else {
        #pragma unroll
        for (int ct = 0; ct < 4; ++ct) {
            #pragma unroll
            for (int rr = 0; rr < 4; ++rr) {
                const int m_l = w * 16 + (l >> 4) * 4 + rr;
                const int n_l = ct * 16 + (l & 15);
                const int m = m0 + m_l;
                const int b = m >> 9, s = m & 511;
                float v = acc[ct][rr] + bias[n0 + n_l];
                const size_t dst = (((size_t)(b * NH + nt) * S_) + s) * HD + n_l;
                if (mat == 0) qbf[dst] = f2bf(v * 0.125f);
                else          kbf[dst] = f2bf(v);
            }
        }
    }
}

// ---------------------------------------------------------------------------
// Kernel 2: scores = qs . K^T + mask -> (b, s, n, k) layout (pure store).
// Batched over (b,n). 64x64 tile.
// ---------------------------------------------------------------------------
__global__ __launch_bounds__(256) void score_qk(
    const short* __restrict__ qbf, const short* __restrict__ kbf,
    const float* __restrict__ mask, float* __restrict__ scores)
{
    __shared__ short qa[64 * 72];
    __shared__ short kb[64 * 72];

    const int st = blockIdx.x, ktile = blockIdx.y, z = blockIdx.z;
    const int b = z / NH, n = z % NH;
    const int s0 = st * 64, k0 = ktile * 64;
    const int tid = threadIdx.x;
    const int w = tid >> 6, l = tid & 63;
    const int sr = tid >> 2, sc = (tid & 3) * 16;

    {
        const short8* sa = (const short8*)(qbf + (((size_t)(b * NH + n) * S_) + s0 + sr) * HD + sc);
        *(short8*)&qa[sr * 72 + sc]     = sa[0];
        *(short8*)&qa[sr * 72 + sc + 8] = sa[1];
        const short8* sb = (const short8*)(kbf + (((size_t)(b * NH + n) * S_) + k0 + sr) * HD + sc);
        *(short8*)&kb[sr * 72 + sc]     = sb[0];
        *(short8*)&kb[sr * 72 + sc + 8] = sb[1];
    }
    __syncthreads();

    f32x4 acc[4];
    #pragma unroll
    for (int i = 0; i < 4; ++i) acc[i] = (f32x4){0.f, 0.f, 0.f, 0.f};

    const int arow = (w * 16 + (l & 15)) * 72 + (l >> 4) * 8;
    short8 a0 = *(const short8*)&qa[arow];
    short8 a1 = *(const short8*)&qa[arow + 32];
    #pragma unroll
    for (int ct = 0; ct < 4; ++ct) {
        const int brow = (ct * 16 + (l & 15)) * 72 + (l >> 4) * 8;
        short8 b0 = *(const short8*)&kb[brow];
        short8 b1 = *(const short8*)&kb[brow + 32];
        acc[ct] = __builtin_amdgcn_mfma_f32_16x16x32_bf16(a0, b0, acc[ct], 0, 0, 0);
        acc[ct] = __builtin_amdgcn_mfma_f32_16x16x32_bf16(a1, b1, acc[ct], 0, 0, 0);
    }

    #pragma unroll
    for (int ct = 0; ct < 4; ++ct) {
        const int kcol = k0 + ct * 16 + (l & 15);
        const float mv = mask[b * S_ + kcol];
        #pragma unroll
        for (int rr = 0; rr < 4; ++rr) {
            const int s_l = w * 16 + (l >> 4) * 4 + rr;
            scores[(((size_t)(b * S_ + s0 + s_l)) * NH + n) * S_ + kcol]
                = acc[ct][rr] + mv;
        }
    }
}

// ---------------------------------------------------------------------------
// Kernel 3: rel contribution, NT rel loads, one 16-k subtile per wave
// (fire-and-exit — this structure sustains the 4.7 TB/s NT demand clamp).
// RMW into scores (b,s,n,k): scores += rel MFMA result.
// Grid (kt=8, s=512, b=2), 256 threads.
// ---------------------------------------------------------------------------
__global__ __launch_bounds__(256) void score_rel(
    const short* __restrict__ qbf,
    const float* __restrict__ rel1, const float* __restrict__ rel2, const float* __restrict__ rel3,
    float* __restrict__ scores)
{
    const int kt = blockIdx.x;       // 0..7
    const int s  = blockIdx.y;
    const int b  = blockIdx.z;
    const int tid = threadIdx.x;
    const int w = tid >> 6, l = tid & 63;

    const int rowsel = l & 15;       // A: n-row / B: k-row / D: k-col
    const int hc     = (l >> 4) * 8; // h-chunk base

    const int kc = kt * 4 + w;       // k-subtile 0..31
    const size_t rbase = ((size_t)(b * S_ + s)) * S_ * HD;
    const size_t ro = rbase + (size_t)(kc * 16 + rowsel) * HD + hc;

    f32x4 p0a = ntload4(rel1 + ro);
    f32x4 p0b = ntload4(rel1 + ro + 4);
    f32x4 q0a = ntload4(rel1 + ro + 32);
    f32x4 q0b = ntload4(rel1 + ro + 36);
    f32x4 p1a = ntload4(rel2 + ro);
    f32x4 p1b = ntload4(rel2 + ro + 4);
    f32x4 q1a = ntload4(rel2 + ro + 32);
    f32x4 q1b = ntload4(rel2 + ro + 36);
    f32x4 p2a = ntload4(rel3 + ro);
    f32x4 p2b = ntload4(rel3 + ro + 4);
    f32x4 q2a = ntload4(rel3 + ro + 32);
    f32x4 q2b = ntload4(rel3 + ro + 36);

    short8 a0 = {0, 0, 0, 0, 0, 0, 0, 0};
    short8 a1 = {0, 0, 0, 0, 0, 0, 0, 0};
    if (rowsel < NH) {
        const short* qp = qbf + (((size_t)(b * NH + rowsel) * S_) + s) * HD;
        a0 = *(const short8*)(qp + hc);
        a1 = *(const short8*)(qp + hc + 32);
    }

    short8 b0 = {
        f2bf(p0a.x + p1a.x + p2a.x), f2bf(p0a.y + p1a.y + p2a.y),
        f2bf(p0a.z + p1a.z + p2a.z), f2bf(p0a.w + p1a.w + p2a.w),
        f2bf(p0b.x + p1b.x + p2b.x), f2bf(p0b.y + p1b.y + p2b.y),
        f2bf(p0b.z + p1b.z + p2b.z), f2bf(p0b.w + p1b.w + p2b.w)};
    short8 b1 = {
        f2bf(q0a.x + q1a.x + q2a.x), f2bf(q0a.y + q1a.y + q2a.y),
        f2bf(q0a.z + q1a.z + q2a.z), f2bf(q0a.w + q1a.w + q2a.w),
        f2bf(q0b.x + q1b.x + q2b.x), f2bf(q0b.y + q1b.y + q2b.y),
        f2bf(q0b.z + q1b.z + q2b.z), f2bf(q0b.w + q1b.w + q2b.w)};

    f32x4 acc = (f32x4){0.f, 0.f, 0.f, 0.f};
    acc = __builtin_amdgcn_mfma_f32_16x16x32_bf16(a0, b0, acc, 0, 0, 0);
    acc = __builtin_amdgcn_mfma_f32_16x16x32_bf16(a1, b1, acc, 0, 0, 0);

    const int kg = kc * 16 + rowsel;
    #pragma unroll
    for (int rr = 0; rr < 4; ++rr) {
        const int n = (l >> 4) * 4 + rr;
        if (n < NH) {
            float* p = scores + (((size_t)(b * S_ + s)) * NH + n) * S_ + kg;
            *p += acc[rr];
        }
    }
}

// ---------------------------------------------------------------------------
// Kernel 4: softmax (global->regs) + MFMA PV. Grid (st=32, n=12, b=2).
// scores rows are contiguous in (b,s,n,k); probs go to bf16 LDS (stride 524
// -> only 2-way bank aliasing, free); PV vs bf16 V^T.
// ---------------------------------------------------------------------------
__global__ __launch_bounds__(256) void smpv(
    const float* __restrict__ scores, const short* __restrict__ vbf,
    float* __restrict__ out)
{
    __shared__ short pbf[16][524];

    const int st  = blockIdx.x;
    const int n   = blockIdx.y;
    const int b   = blockIdx.z;
    const int s0  = st * 16;
    const int tid = threadIdx.x;
    const int w = tid >> 6, l = tid & 63;

    // --- softmax: wave w owns rows w*4..w*4+3 (PB-Relax == plain softmax) ---
    for (int r = 0; r < 4; ++r) {
        const int row = w * 4 + r;
        const float* sp = scores + (((size_t)(b * S_ + s0 + row)) * NH + n) * S_;
        float vals[8];
        float m = -1e30f;
        #pragma unroll
        for (int i = 0; i < 8; ++i) { vals[i] = sp[l + 64 * i]; m = fmaxf(m, vals[i]); }
        #pragma unroll
        for (int off = 32; off >= 1; off >>= 1) m = fmaxf(m, __shfl_xor(m, off));
        float sum = 0.f;
        #pragma unroll
        for (int i = 0; i < 8; ++i) { vals[i] = __expf(vals[i] - m); sum += vals[i]; }
        #pragma unroll
        for (int off = 32; off >= 1; off >>= 1) sum += __shfl_xor(sum, off);
        const float inv = 1.0f / sum;
        #pragma unroll
        for (int i = 0; i < 8; ++i) pbf[row][l + 64 * i] = f2bf(vals[i] * inv);
    }
    __syncthreads();

    // --- PV via MFMA: out[s][h] = sum_k P[s][k] V^T[h][k]. Wave w owns
    // h-tile w (16 h). 16 K-steps of 32. ---
    const int arow = l & 15;
    const int g    = l >> 4;
    f32x4 pacc = (f32x4){0.f, 0.f, 0.f, 0.f};
    const short* vrow = vbf + ((size_t)(b * NH + n) * HD + w * 16 + arow) * S_ + g * 8;
    #pragma unroll
    for (int kk = 0; kk < 16; ++kk) {
        short8 aP = *(const short8*)&pbf[arow][kk * 32 + g * 8];
        short8 bV = *(const short8*)(vrow + kk * 32);
        pacc = __builtin_amdgcn_mfma_f32_16x16x32_bf16(aP, bV, pacc, 0, 0, 0);
    }
    #pragma unroll
    for (int rr = 0; rr < 4; ++rr) {
        const int srow = g * 4 + rr;
        out[((size_t)(b * S_ + s0 + srow)) * D_ + n * HD + w * 16 + arow] = pacc[rr];
    }
}

extern "C" void kernel_launch(void* const* d_in, const int* in_sizes, int n_in,
                              void* d_out, int out_size, void* d_ws, size_t ws_size,
                              hipStream_t stream) {
    const float* hidden = (const float*)d_in[0];
    const float* mask   = (const float*)d_in[1];
    const float* rel1   = (const float*)d_in[2];
    const float* rel2   = (const float*)d_in[3];
    const float* rel3   = (const float*)d_in[4];
    const float* Wq     = (const float*)d_in[5];
    const float* bq     = (const float*)d_in[6];
    const float* Wk     = (const float*)d_in[7];
    const float* bk     = (const float*)d_in[8];
    const float* Wv     = (const float*)d_in[9];
    const float* bv     = (const float*)d_in[10];
    float* out = (float*)d_out;

    const size_t per = (size_t)B_ * NH * S_ * HD;   // 786432
    short* qbf    = (short*)d_ws;                    // 1.5 MB
    short* kbf    = qbf + per;                       // 1.5 MB
    short* vbf    = kbf + per;                       // 1.5 MB (b,n,h,s)
    float* scores = (float*)(vbf + per);             // 25 MB (b,s,n,k)

    qkv_gemm<<<dim3(16, 12, 3), 256, 0, stream>>>(hidden, Wq, Wk, Wv, bq, bk, bv, qbf, kbf, vbf);
    score_qk<<<dim3(8, 8, 24), 256, 0, stream>>>(qbf, kbf, mask, scores);
    score_rel<<<dim3(8, S_, B_), 256, 0, stream>>>(qbf, rel1, rel2, rel3, scores);
    smpv<<<dim3(S_ / 16, NH, B_), 256, 0, stream>>>(scores, vbf, out);
}